// Round 20
// baseline (69.702 us; speedup 1.0000x reference)
//
#include <hip/hip_runtime.h>
#include <hip/hip_fp16.h>
#include <cstdint>

#define N_NODES 4096
#define F_IN    512
#define F_OUT   64
#define H_HEADS 8
#define JC      4          // j-sweep chunks for k_attn_mfma

constexpr float L2E = 1.44269504088896f;

typedef _Float16 half2_t __attribute__((ext_vector_type(2)));
typedef _Float16 half4_t __attribute__((ext_vector_type(4)));
typedef _Float16 half8_t __attribute__((ext_vector_type(8)));
typedef float    f32x4   __attribute__((ext_vector_type(4)));

// ---------------- K0: merged W-pack (blocks 0..127) + adj bitmask -> adjwT (blocks 128..2175) ----------------
__global__ __launch_bounds__(256) void k_prep(const int* __restrict__ adj,
                                              const float* __restrict__ W,
                                              unsigned long long* __restrict__ adjwT,
                                              _Float16* __restrict__ wfrag) {
    if (blockIdx.x < 128) {
        int gid = blockIdx.x * 256 + threadIdx.x;         // 0 .. 32767
        int h     = gid >> 12;
        int kt    = (gid >> 8) & 15;
        int ntile = (gid >> 6) & 3;
        int lane  = gid & 63;
        int c0 = lane & 15, g = lane >> 4;
        const float* src = W + ((size_t)h * F_IN + kt * 32 + 8 * g) * F_OUT + ntile * 16 + c0;
        half8_t hv;
        #pragma unroll
        for (int t = 0; t < 8; t++) hv[t] = (_Float16)src[(size_t)t * F_OUT];
        *reinterpret_cast<half8_t*>(&wfrag[(size_t)gid * 8]) = hv;
        return;
    }
    int bid  = blockIdx.x - 128;                          // 0..2047
    int lane = threadIdx.x & 63;
    int wid  = (int)((bid * 256 + threadIdx.x) >> 6);
    int nwaves = (2048 * 256) >> 6;
    const int nchunks = N_NODES * (N_NODES / 64);
    for (int cf = wid; cf < nchunks; cf += nwaves) {
        int v = adj[(size_t)cf * 64 + lane];
        unsigned long long mask = __ballot(v > 0);
        if (lane == 0) {
            int i = cf >> 6, c = cf & 63;
            adjwT[(size_t)c * N_NODES + i] = mask;        // [c][i] for k_attn
        }
    }
}

// ---------------- K1: Wh = x @ W[h] via MFMA 16x16x32, x shared across all 8 heads ----------------
// grid 256 (one 16-row x-tile per block), block 512 = 8 waves, wave w = head h.
__global__ __launch_bounds__(512) void k_wh_mfma(const float* __restrict__ x,
                                                 const _Float16* __restrict__ wfrag,
                                                 const float* __restrict__ a_src,
                                                 const float* __restrict__ a_tgt,
                                                 _Float16* __restrict__ WhFrag,
                                                 float* __restrict__ s_iL,
                                                 float* __restrict__ s_jL) {
    __shared__ _Float16 xs[16 * 512];     // [row(16)][512 f16], 16B-unit swizzled
    const int rt   = blockIdx.x;          // 16-row m-tile index == mt (0..255)
    const int t    = threadIdx.x;
    const int lane = t & 63;
    const int h    = t >> 6;              // wave = head
    const int c0   = lane & 15;
    const int gl   = lane >> 4;

    {   // stage x tile: coalesced f32 loads, cvt f16, swizzled 16B-unit writes
        const int srow = t >> 5;          // 0..15
        const int seg  = t & 31;          // 16-f32 segment within row
        const float* src = x + (size_t)(rt * 16 + srow) * F_IN + seg * 16;
        _Float16* drow = &xs[srow * 512];
        #pragma unroll
        for (int j = 0; j < 2; j++) {
            float4 v0 = *reinterpret_cast<const float4*>(src + j * 8);
            float4 v1 = *reinterpret_cast<const float4*>(src + j * 8 + 4);
            half8_t hv;
            hv[0] = (_Float16)v0.x; hv[1] = (_Float16)v0.y; hv[2] = (_Float16)v0.z; hv[3] = (_Float16)v0.w;
            hv[4] = (_Float16)v1.x; hv[5] = (_Float16)v1.y; hv[6] = (_Float16)v1.z; hv[7] = (_Float16)v1.w;
            int u  = seg * 2 + j;
            int up = u ^ (srow & 7);
            *reinterpret_cast<half8_t*>(&drow[up * 8]) = hv;
        }
    }
    __syncthreads();

    f32x4 acc0 = {0.f, 0.f, 0.f, 0.f};
    f32x4 acc1 = {0.f, 0.f, 0.f, 0.f};
    f32x4 acc2 = {0.f, 0.f, 0.f, 0.f};
    f32x4 acc3 = {0.f, 0.f, 0.f, 0.f};

    const _Float16* __restrict__ Bf   = wfrag + (size_t)h * (16 * 4 * 512) + (size_t)lane * 8;
    const _Float16* __restrict__ arow = &xs[c0 * 512];

    #pragma unroll
    for (int kt = 0; kt < 16; kt++) {
        int up = (kt * 4 + gl) ^ (c0 & 7);
        half8_t a = *reinterpret_cast<const half8_t*>(&arow[up * 8]);
        const _Float16* Bk = Bf + (size_t)kt * 2048;
        half8_t b0 = *reinterpret_cast<const half8_t*>(Bk);
        half8_t b1 = *reinterpret_cast<const half8_t*>(Bk + 512);
        half8_t b2 = *reinterpret_cast<const half8_t*>(Bk + 1024);
        half8_t b3 = *reinterpret_cast<const half8_t*>(Bk + 1536);
        acc0 = __builtin_amdgcn_mfma_f32_16x16x32_f16(a, b0, acc0, 0, 0, 0);
        acc1 = __builtin_amdgcn_mfma_f32_16x16x32_f16(a, b1, acc1, 0, 0, 0);
        acc2 = __builtin_amdgcn_mfma_f32_16x16x32_f16(a, b2, acc2, 0, 0, 0);
        acc3 = __builtin_amdgcn_mfma_f32_16x16x32_f16(a, b3, acc3, 0, 0, 0);
    }

    const float as0 = a_src[h * 64 + c0],      at0 = a_tgt[h * 64 + c0];
    const float as1 = a_src[h * 64 + 16 + c0], at1 = a_tgt[h * 64 + 16 + c0];
    const float as2 = a_src[h * 64 + 32 + c0], at2 = a_tgt[h * 64 + 32 + c0];
    const float as3 = a_src[h * 64 + 48 + c0], at3 = a_tgt[h * 64 + 48 + c0];

    #pragma unroll
    for (int reg = 0; reg < 4; reg++) {
        float vi = acc0[reg] * as0 + acc1[reg] * as1 + acc2[reg] * as2 + acc3[reg] * as3;
        float vj = acc0[reg] * at0 + acc1[reg] * at1 + acc2[reg] * at2 + acc3[reg] * at3;
        #pragma unroll
        for (int mm = 8; mm >= 1; mm >>= 1) {
            vi += __shfl_xor(vi, mm, 64);
            vj += __shfl_xor(vj, mm, 64);
        }
        if (c0 == 0) {
            int row = rt * 16 + 4 * gl + reg;
            s_iL[h * N_NODES + row] = vi * L2E;
            s_jL[h * N_NODES + row] = vj * L2E;
        }
    }

    // WhFrag fragment write (mt = rt)
    const int cc    = rt >> 2;
    const int kb    = (rt >> 1) & 1;
    const int lanep = c0 + 16 * ((rt & 1) * 2 + (gl >> 1));
    const int tb    = 4 * (gl & 1);
    _Float16* dst = WhFrag + (size_t)h * (N_NODES * 64)
                  + (size_t)(cc * 2 + kb) * 2048 + (size_t)lanep * 8 + tb;
    f32x4 accs[4] = {acc0, acc1, acc2, acc3};
    #pragma unroll
    for (int ot = 0; ot < 4; ot++) {
        half4_t hv;
        #pragma unroll
        for (int reg = 0; reg < 4; reg++) hv[reg] = (_Float16)accs[ot][reg];
        *reinterpret_cast<half4_t*>(dst + ot * 512) = hv;
    }
}

// ---------------- K2: per-head max of s_jL + factor tables F1=exp2(sj-mx), F2=exp2(0.2(sj-mx)) ----------------
__global__ __launch_bounds__(256) void k_hmax(const float* __restrict__ s_jL,
                                              float* __restrict__ mxAll,
                                              _Float16* __restrict__ F1h,
                                              _Float16* __restrict__ F2h) {
    __shared__ float red[4];
    __shared__ float mxs;
    const int h = blockIdx.x;
    const int t = threadIdx.x;
    const float* p = s_jL + h * N_NODES;
    float v[16];
    float m = -INFINITY;
    #pragma unroll
    for (int i = 0; i < 16; i++) {
        v[i] = p[t + i * 256];
        m = fmaxf(m, v[i]);
    }
    #pragma unroll
    for (int mm = 32; mm >= 1; mm >>= 1) m = fmaxf(m, __shfl_xor(m, mm, 64));
    if ((t & 63) == 0) red[t >> 6] = m;
    __syncthreads();
    if (t == 0) {
        float mx = fmaxf(fmaxf(red[0], red[1]), fmaxf(red[2], red[3]));
        mxAll[h] = mx;
        mxs = mx;
    }
    __syncthreads();
    const float mx = mxs;
    #pragma unroll
    for (int i = 0; i < 16; i++) {
        float d = v[i] - mx;                      // <= 0
        F1h[h * N_NODES + t + i * 256] = (_Float16)exp2f(d);
        F2h[h * N_NODES + t + i * 256] = (_Float16)exp2f(0.2f * d);
    }
}

// ---------------- K3: exp-free P + 2-chunk-deep LDS staging (barrier per 2 c) + nibble masks ----------------
// grid (32, 8, JC), block 256 (4 waves). Wave: rows i0..i0+31 (two 16-row tiles), 64 o.
__global__ __launch_bounds__(256, 4) void k_attn_mfma(const _Float16* __restrict__ WhFrag,
                                                      const float* __restrict__ s_iL,
                                                      const float* __restrict__ mxAll,
                                                      const _Float16* __restrict__ F1h,
                                                      const _Float16* __restrict__ F2h,
                                                      const unsigned long long* __restrict__ adjwT,
                                                      float* __restrict__ out0,
                                                      _Float16* __restrict__ partH,
                                                      float* __restrict__ lbuf) {
    __shared__ uint2 ktab4[16];             // nibble -> 2 packed halfword KEEP masks (128B: conflict-free)
    __shared__ _Float16 Bs[2][8192];        // 2 x 16KB: TWO c-chunks per buffer (barrier per 2 c)
    if (threadIdx.x < 16) {
        unsigned int nib = threadIdx.x;
        unsigned int w0 = ((nib & 1u) ? 0xFFFFu : 0u) | ((nib & 2u) ? 0xFFFF0000u : 0u);
        unsigned int w1 = ((nib & 4u) ? 0xFFFFu : 0u) | ((nib & 8u) ? 0xFFFF0000u : 0u);
        ktab4[nib] = make_uint2(w0, w1);
    }

    const int tid  = threadIdx.x;
    const int h    = blockIdx.y;
    const int jc   = blockIdx.z;
    const int lane = tid & 63;
    const int w    = tid >> 6;
    const int i0   = blockIdx.x * 128 + w * 32;     // wave's 32 rows
    const int mrow = lane & 15;
    const int gl   = lane >> 4;
    const int gl8  = gl << 3;

    const float siL0 = s_iL[h * N_NODES + i0 + mrow];
    const float siL1 = s_iL[h * N_NODES + i0 + 16 + mrow];
    const float mxh  = mxAll[h];
    const float tm0 = siL0 + mxh, tm1 = siL1 + mxh;
    const float m0 = fmaxf(tm0, 0.2f * tm0);
    const float m1 = fmaxf(tm1, 0.2f * tm1);
    const _Float16 E1A = (_Float16)exp2f(tm0 - m0);
    const _Float16 E2A = (_Float16)exp2f(fmaf(0.2f, tm0, -m0));
    const _Float16 E1B = (_Float16)exp2f(tm1 - m1);
    const _Float16 E2B = (_Float16)exp2f(fmaf(0.2f, tm1, -m1));
    const half2_t e1a = {E1A, E1A}, e2a = {E2A, E2A};
    const half2_t e1b = {E1B, E1B}, e2b = {E2B, E2B};

    const _Float16* __restrict__ F1 = F1h + h * N_NODES;
    const _Float16* __restrict__ F2 = F2h + h * N_NODES;
    const _Float16* __restrict__ Bh = WhFrag + (size_t)h * (N_NODES * 64);

    half8_t vone;
    #pragma unroll
    for (int q = 0; q < 8; q++) vone[q] = (_Float16)1.0f;

    f32x4 accA0 = {0,0,0,0}, accA1 = {0,0,0,0}, accA2 = {0,0,0,0}, accA3 = {0,0,0,0};
    f32x4 accB0 = {0,0,0,0}, accB1 = {0,0,0,0}, accB2 = {0,0,0,0}, accB3 = {0,0,0,0};
    f32x4 acclA = {0,0,0,0}, acclB = {0,0,0,0};

    const int NC   = (N_NODES / 64) / JC;   // 16
    const int cbeg = jc * NC;
    const int cend = cbeg + NC;

    {   // prologue: stage chunk pair (cbeg, cbeg+1) into Bs[0]
        #pragma unroll
        for (int s = 0; s < 4; s++)
            *reinterpret_cast<half8_t*>(&Bs[0][s * 2048 + tid * 8]) =
                *reinterpret_cast<const half8_t*>(Bh + (size_t)cbeg * 4096 + s * 2048 + tid * 8);
    }
    __syncthreads();

    int cur = 0;
    for (int cp = cbeg; cp < cend; cp += 2) {
        half8_t nx0, nx1, nx2, nx3;
        const bool hasNext = (cp + 2 < cend);
        if (hasNext) {
            const _Float16* src = Bh + (size_t)(cp + 2) * 4096 + tid * 8;
            nx0 = *reinterpret_cast<const half8_t*>(src);
            nx1 = *reinterpret_cast<const half8_t*>(src + 2048);
            nx2 = *reinterpret_cast<const half8_t*>(src + 4096);
            nx3 = *reinterpret_cast<const half8_t*>(src + 6144);
        }

        #pragma unroll
        for (int ci = 0; ci < 2; ci++) {
            const int c = cp + ci;
            uint2 word0 = *reinterpret_cast<const uint2*>(&adjwT[(size_t)c * N_NODES + i0 + mrow]);
            uint2 word1 = *reinterpret_cast<const uint2*>(&adjwT[(size_t)c * N_NODES + i0 + 16 + mrow]);

            #pragma unroll
            for (int kb = 0; kb < 2; kb++) {
                const int jb = c * 64 + kb * 32 + 8 * gl;
                half8_t f1v = *reinterpret_cast<const half8_t*>(&F1[jb]);
                half8_t f2v = *reinterpret_cast<const half8_t*>(&F2[jb]);
                unsigned int bm0 = ((kb ? word0.y : word0.x) >> gl8) & 0xFFu;
                unsigned int bm1 = ((kb ? word1.y : word1.x) >> gl8) & 0xFFu;
                uint2 klo0 = ktab4[bm0 & 15u], khi0 = ktab4[bm0 >> 4];
                uint2 klo1 = ktab4[bm1 & 15u], khi1 = ktab4[bm1 >> 4];
                uint4 mk0 = {klo0.x, klo0.y, khi0.x, khi0.y};
                uint4 mk1 = {klo1.x, klo1.y, khi1.x, khi1.y};

                uint4 f1u = __builtin_bit_cast(uint4, f1v);
                uint4 f2u = __builtin_bit_cast(uint4, f2v);
                uint4 p0u, p1u;
                #pragma unroll
                for (int q = 0; q < 4; q++) {
                    unsigned int f1w = (q == 0) ? f1u.x : (q == 1) ? f1u.y : (q == 2) ? f1u.z : f1u.w;
                    unsigned int f2w = (q == 0) ? f2u.x : (q == 1) ? f2u.y : (q == 2) ? f2u.z : f2u.w;
                    half2_t f12 = __builtin_bit_cast(half2_t, f1w);
                    half2_t f22 = __builtin_bit_cast(half2_t, f2w);
                    half2_t pA = __builtin_elementwise_max(e1a * f12, e2a * f22);  // exp-free P
                    half2_t pB = __builtin_elementwise_max(e1b * f12, e2b * f22);
                    unsigned int ka  = (q == 0) ? mk0.x : (q == 1) ? mk0.y : (q == 2) ? mk0.z : mk0.w;
                    unsigned int kbm = (q == 0) ? mk1.x : (q == 1) ? mk1.y : (q == 2) ? mk1.z : mk1.w;
                    unsigned int pa = __builtin_bit_cast(unsigned int, pA) & ka;
                    unsigned int pb = __builtin_bit_cast(unsigned int, pB) & kbm;
                    if (q == 0) { p0u.x = pa; p1u.x = pb; }
                    else if (q == 1) { p0u.y = pa; p1u.y = pb; }
                    else if (q == 2) { p0u.z = pa; p1u.z = pb; }
                    else { p0u.w = pa; p1u.w = pb; }
                }
                half8_t af0 = __builtin_bit_cast(half8_t, p0u);
                half8_t af1 = __builtin_bit_cast(half8_t, p1u);

                const _Float16* Bk = &Bs[cur][ci * 4096 + kb * 2048 + lane * 8];
                half8_t b0  = *reinterpret_cast<const half8_t*>(Bk);
                half8_t b1v = *reinterpret_cast<const half8_t*>(Bk + 512);
                half8_t b2  = *reinterpret_cast<const half8_t*>(Bk + 1024);
                half8_t b3  = *reinterpret_cast<const half8_t*>(Bk + 1536);

                accA0 = __builtin_amdgcn_mfma_f32_16x16x32_f16(af0, b0,  accA0, 0, 0, 0);
                accB0 = __builtin_amdgcn_mfma_f32_16x16x32_f16(af1, b0,  accB0, 0, 0, 0);
                accA1 = __builtin_amdgcn_mfma_f32_16x16x32_f16(af0, b1v, accA1, 0, 0, 0);
                accB1 = __builtin_amdgcn_mfma_f32_16x16x32_f16(af1, b1v, accB1, 0, 0, 0);
                accA2 = __builtin_amdgcn_mfma_f32_16x16x32_f16(af0, b2,  accA2, 0, 0, 0);
                accB2 = __builtin_amdgcn_mfma_f32_16x16x32_f16(af1, b2,  accB2, 0, 0, 0);
                accA3 = __builtin_amdgcn_mfma_f32_16x16x32_f16(af0, b3,  accA3, 0, 0, 0);
                accB3 = __builtin_amdgcn_mfma_f32_16x16x32_f16(af1, b3,  accB3, 0, 0, 0);
                acclA = __builtin_amdgcn_mfma_f32_16x16x32_f16(af0, vone, acclA, 0, 0, 0);
                acclB = __builtin_amdgcn_mfma_f32_16x16x32_f16(af1, vone, acclB, 0, 0, 0);
            }
        }

        if (hasNext) {
            *reinterpret_cast<half8_t*>(&Bs[cur ^ 1][tid * 8])        = nx0;
            *reinterpret_cast<half8_t*>(&Bs[cur ^ 1][2048 + tid * 8]) = nx1;
            *reinterpret_cast<half8_t*>(&Bs[cur ^ 1][4096 + tid * 8]) = nx2;
            *reinterpret_cast<half8_t*>(&Bs[cur ^ 1][6144 + tid * 8]) = nx3;
        }
        __syncthreads();
        cur ^= 1;
    }

    float* lp = lbuf + (size_t)jc * (H_HEADS * N_NODES);
    if (mrow == 0) {
        #pragma unroll
        for (int r = 0; r < 4; r++) {
            lp[h * N_NODES + i0 + 4 * gl + r]      = acclA[r];
            lp[h * N_NODES + i0 + 16 + 4 * gl + r] = acclB[r];
        }
    }
    if (jc == 0) {
        #pragma unroll
        for (int r = 0; r < 4; r++) {
            size_t obA = ((size_t)h * N_NODES + i0 + 4 * gl + r) * 64 + mrow;
            size_t obB = ((size_t)h * N_NODES + i0 + 16 + 4 * gl + r) * 64 + mrow;
            out0[obA + 0]  = accA0[r];
            out0[obA + 16] = accA1[r];
            out0[obA + 32] = accA2[r];
            out0[obA + 48] = accA3[r];
            out0[obB + 0]  = accB0[r];
            out0[obB + 16] = accB1[r];
            out0[obB + 32] = accB2[r];
            out0[obB + 48] = accB3[r];
        }
    } else {
        _Float16* op = partH + (size_t)(jc - 1) * ((size_t)H_HEADS * N_NODES * F_OUT);
        #pragma unroll
        for (int r = 0; r < 4; r++) {
            size_t obA = ((size_t)h * N_NODES + i0 + 4 * gl + r) * 64 + mrow;
            size_t obB = ((size_t)h * N_NODES + i0 + 16 + 4 * gl + r) * 64 + mrow;
            op[obA + 0]  = (_Float16)accA0[r];
            op[obA + 16] = (_Float16)accA1[r];
            op[obA + 32] = (_Float16)accA2[r];
            op[obA + 48] = (_Float16)accA3[r];
            op[obB + 0]  = (_Float16)accB0[r];
            op[obB + 16] = (_Float16)accB1[r];
            op[obB + 32] = (_Float16)accB2[r];
            op[obB + 48] = (_Float16)accB3[r];
        }
    }
}

// ---------------- K4: out = (out + sum f16 partials) / sum l ----------------
__global__ __launch_bounds__(256) void k_norm(float* __restrict__ out,
                                              const _Float16* __restrict__ partH,
                                              const float* __restrict__ lbuf) {
    const int HN = H_HEADS * N_NODES;
    int idx = blockIdx.x * 256 + threadIdx.x;        // float4 index
    int row = idx >> 4;
    float inv = 1.0f / (lbuf[row] + lbuf[HN + row] + lbuf[2 * HN + row] + lbuf[3 * HN + row]);
    float4 a = reinterpret_cast<const float4*>(out)[idx];
    float s0 = a.x, s1 = a.y, s2 = a.z, s3 = a.w;
    #pragma unroll
    for (int p = 0; p < 3; p++) {
        half4_t hp = *reinterpret_cast<const half4_t*>(
            &partH[(size_t)p * ((size_t)H_HEADS * N_NODES * F_OUT) + (size_t)idx * 4]);
        s0 += (float)hp[0]; s1 += (float)hp[1]; s2 += (float)hp[2]; s3 += (float)hp[3];
    }
    float4 v = {s0 * inv, s1 * inv, s2 * inv, s3 * inv};
    reinterpret_cast<float4*>(out)[idx] = v;
}

// ---------------- launch ----------------
extern "C" void kernel_launch(void* const* d_in, const int* in_sizes, int n_in,
                              void* d_out, int out_size, void* d_ws, size_t ws_size,
                              hipStream_t stream) {
    const float* x     = (const float*)d_in[0];
    const int*   adj   = (const int*)d_in[1];
    const float* W     = (const float*)d_in[2];
    const float* a_src = (const float*)d_in[3];
    const float* a_tgt = (const float*)d_in[4];
    float* out = (float*)d_out;

    // workspace via accumulating allocator (R7 lesson: no hand-computed offsets)
    char* ws = (char*)d_ws;
    size_t off = 0;
    auto alloc = [&](size_t bytes) -> char* {
        char* p = ws + off;
        off += (bytes + 255) & ~(size_t)255;
        return p;
    };
    _Float16* WhFrag = (_Float16*)alloc((size_t)H_HEADS * N_NODES * F_OUT * 2);        // 4 MB
    _Float16* wfrag  = (_Float16*)alloc((size_t)H_HEADS * 16 * 4 * 64 * 8 * 2);        // 512 KB
    float* s_iL      = (float*)alloc((size_t)H_HEADS * N_NODES * 4);                   // 128 KB
    float* s_jL      = (float*)alloc((size_t)H_HEADS * N_NODES * 4);                   // 128 KB
    _Float16* F1h    = (_Float16*)alloc((size_t)H_HEADS * N_NODES * 2);                // 64 KB
    _Float16* F2h    = (_Float16*)alloc((size_t)H_HEADS * N_NODES * 2);                // 64 KB
    float* mxAll     = (float*)alloc((size_t)H_HEADS * 4);                             // 32 B
    float* lbuf      = (float*)alloc((size_t)JC * H_HEADS * N_NODES * 4);              // 512 KB
    _Float16* partH  = (_Float16*)alloc((size_t)(JC - 1) * H_HEADS * N_NODES * F_OUT * 2); // 12 MB
    unsigned long long* adjwT = (unsigned long long*)alloc((size_t)N_NODES * (N_NODES / 64) * 8); // 2 MB
    (void)ws_size;

    k_prep<<<2176, 256, 0, stream>>>(adj, W, adjwT, wfrag);
    k_wh_mfma<<<N_NODES / 16, 512, 0, stream>>>(x, wfrag, a_src, a_tgt, WhFrag, s_iL, s_jL);
    k_hmax<<<H_HEADS, 256, 0, stream>>>(s_jL, mxAll, F1h, F2h);
    k_attn_mfma<<<dim3(N_NODES / 128, H_HEADS, JC), 256, 0, stream>>>(WhFrag, s_iL, mxAll, F1h, F2h,
                                                                      adjwT, out, partH, lbuf);
    k_norm<<<(H_HEADS * N_NODES * F_OUT / 4) / 256, 256, 0, stream>>>(out, partH, lbuf);
}

// Round 21
// 68.408 us; speedup vs baseline: 1.0189x; 1.0189x over previous
//
#include <hip/hip_runtime.h>
#include <hip/hip_fp16.h>
#include <cstdint>

#define N_NODES 4096
#define F_IN    512
#define F_OUT   64
#define H_HEADS 8
#define JC      4          // j-sweep chunks for k_attn_mfma

constexpr float L2E = 1.44269504088896f;

typedef _Float16 half2_t __attribute__((ext_vector_type(2)));
typedef _Float16 half4_t __attribute__((ext_vector_type(4)));
typedef _Float16 half8_t __attribute__((ext_vector_type(8)));
typedef float    f32x4   __attribute__((ext_vector_type(4)));

// ---------------- K0: merged W-pack (blocks 0..127) + adj bitmask -> adjwT (blocks 128..2175) ----------------
__global__ __launch_bounds__(256) void k_prep(const int* __restrict__ adj,
                                              const float* __restrict__ W,
                                              unsigned long long* __restrict__ adjwT,
                                              _Float16* __restrict__ wfrag) {
    if (blockIdx.x < 128) {
        int gid = blockIdx.x * 256 + threadIdx.x;         // 0 .. 32767
        int h     = gid >> 12;
        int kt    = (gid >> 8) & 15;
        int ntile = (gid >> 6) & 3;
        int lane  = gid & 63;
        int c0 = lane & 15, g = lane >> 4;
        const float* src = W + ((size_t)h * F_IN + kt * 32 + 8 * g) * F_OUT + ntile * 16 + c0;
        half8_t hv;
        #pragma unroll
        for (int t = 0; t < 8; t++) hv[t] = (_Float16)src[(size_t)t * F_OUT];
        *reinterpret_cast<half8_t*>(&wfrag[(size_t)gid * 8]) = hv;
        return;
    }
    int bid  = blockIdx.x - 128;                          // 0..2047
    int lane = threadIdx.x & 63;
    int wid  = (int)((bid * 256 + threadIdx.x) >> 6);
    int nwaves = (2048 * 256) >> 6;
    const int nchunks = N_NODES * (N_NODES / 64);
    for (int cf = wid; cf < nchunks; cf += nwaves) {
        int v = adj[(size_t)cf * 64 + lane];
        unsigned long long mask = __ballot(v > 0);
        if (lane == 0) {
            int i = cf >> 6, c = cf & 63;
            adjwT[(size_t)c * N_NODES + i] = mask;        // [c][i] for k_attn
        }
    }
}

// ---------------- K1: Wh = x @ W[h] via MFMA 16x16x32, x shared across all 8 heads ----------------
// grid 256 (one 16-row x-tile per block), block 512 = 8 waves, wave w = head h.
__global__ __launch_bounds__(512) void k_wh_mfma(const float* __restrict__ x,
                                                 const _Float16* __restrict__ wfrag,
                                                 const float* __restrict__ a_src,
                                                 const float* __restrict__ a_tgt,
                                                 _Float16* __restrict__ WhFrag,
                                                 float* __restrict__ s_iL,
                                                 float* __restrict__ s_jL) {
    __shared__ _Float16 xs[16 * 512];     // [row(16)][512 f16], 16B-unit swizzled
    const int rt   = blockIdx.x;          // 16-row m-tile index == mt (0..255)
    const int t    = threadIdx.x;
    const int lane = t & 63;
    const int h    = t >> 6;              // wave = head
    const int c0   = lane & 15;
    const int gl   = lane >> 4;

    {   // stage x tile: coalesced f32 loads, cvt f16, swizzled 16B-unit writes
        const int srow = t >> 5;          // 0..15
        const int seg  = t & 31;          // 16-f32 segment within row
        const float* src = x + (size_t)(rt * 16 + srow) * F_IN + seg * 16;
        _Float16* drow = &xs[srow * 512];
        #pragma unroll
        for (int j = 0; j < 2; j++) {
            float4 v0 = *reinterpret_cast<const float4*>(src + j * 8);
            float4 v1 = *reinterpret_cast<const float4*>(src + j * 8 + 4);
            half8_t hv;
            hv[0] = (_Float16)v0.x; hv[1] = (_Float16)v0.y; hv[2] = (_Float16)v0.z; hv[3] = (_Float16)v0.w;
            hv[4] = (_Float16)v1.x; hv[5] = (_Float16)v1.y; hv[6] = (_Float16)v1.z; hv[7] = (_Float16)v1.w;
            int u  = seg * 2 + j;
            int up = u ^ (srow & 7);
            *reinterpret_cast<half8_t*>(&drow[up * 8]) = hv;
        }
    }
    __syncthreads();

    f32x4 acc0 = {0.f, 0.f, 0.f, 0.f};
    f32x4 acc1 = {0.f, 0.f, 0.f, 0.f};
    f32x4 acc2 = {0.f, 0.f, 0.f, 0.f};
    f32x4 acc3 = {0.f, 0.f, 0.f, 0.f};

    const _Float16* __restrict__ Bf   = wfrag + (size_t)h * (16 * 4 * 512) + (size_t)lane * 8;
    const _Float16* __restrict__ arow = &xs[c0 * 512];

    #pragma unroll
    for (int kt = 0; kt < 16; kt++) {
        int up = (kt * 4 + gl) ^ (c0 & 7);
        half8_t a = *reinterpret_cast<const half8_t*>(&arow[up * 8]);
        const _Float16* Bk = Bf + (size_t)kt * 2048;
        half8_t b0 = *reinterpret_cast<const half8_t*>(Bk);
        half8_t b1 = *reinterpret_cast<const half8_t*>(Bk + 512);
        half8_t b2 = *reinterpret_cast<const half8_t*>(Bk + 1024);
        half8_t b3 = *reinterpret_cast<const half8_t*>(Bk + 1536);
        acc0 = __builtin_amdgcn_mfma_f32_16x16x32_f16(a, b0, acc0, 0, 0, 0);
        acc1 = __builtin_amdgcn_mfma_f32_16x16x32_f16(a, b1, acc1, 0, 0, 0);
        acc2 = __builtin_amdgcn_mfma_f32_16x16x32_f16(a, b2, acc2, 0, 0, 0);
        acc3 = __builtin_amdgcn_mfma_f32_16x16x32_f16(a, b3, acc3, 0, 0, 0);
    }

    const float as0 = a_src[h * 64 + c0],      at0 = a_tgt[h * 64 + c0];
    const float as1 = a_src[h * 64 + 16 + c0], at1 = a_tgt[h * 64 + 16 + c0];
    const float as2 = a_src[h * 64 + 32 + c0], at2 = a_tgt[h * 64 + 32 + c0];
    const float as3 = a_src[h * 64 + 48 + c0], at3 = a_tgt[h * 64 + 48 + c0];

    #pragma unroll
    for (int reg = 0; reg < 4; reg++) {
        float vi = acc0[reg] * as0 + acc1[reg] * as1 + acc2[reg] * as2 + acc3[reg] * as3;
        float vj = acc0[reg] * at0 + acc1[reg] * at1 + acc2[reg] * at2 + acc3[reg] * at3;
        #pragma unroll
        for (int mm = 8; mm >= 1; mm >>= 1) {
            vi += __shfl_xor(vi, mm, 64);
            vj += __shfl_xor(vj, mm, 64);
        }
        if (c0 == 0) {
            int row = rt * 16 + 4 * gl + reg;
            s_iL[h * N_NODES + row] = vi * L2E;
            s_jL[h * N_NODES + row] = vj * L2E;
        }
    }

    // WhFrag fragment write (mt = rt)
    const int cc    = rt >> 2;
    const int kb    = (rt >> 1) & 1;
    const int lanep = c0 + 16 * ((rt & 1) * 2 + (gl >> 1));
    const int tb    = 4 * (gl & 1);
    _Float16* dst = WhFrag + (size_t)h * (N_NODES * 64)
                  + (size_t)(cc * 2 + kb) * 2048 + (size_t)lanep * 8 + tb;
    f32x4 accs[4] = {acc0, acc1, acc2, acc3};
    #pragma unroll
    for (int ot = 0; ot < 4; ot++) {
        half4_t hv;
        #pragma unroll
        for (int reg = 0; reg < 4; reg++) hv[reg] = (_Float16)accs[ot][reg];
        *reinterpret_cast<half4_t*>(dst + ot * 512) = hv;
    }
}

// ---------------- K2: per-head max of s_jL + factor tables F1=exp2(sj-mx), F2=exp2(0.2(sj-mx)) ----------------
__global__ __launch_bounds__(256) void k_hmax(const float* __restrict__ s_jL,
                                              float* __restrict__ mxAll,
                                              _Float16* __restrict__ F1h,
                                              _Float16* __restrict__ F2h) {
    __shared__ float red[4];
    __shared__ float mxs;
    const int h = blockIdx.x;
    const int t = threadIdx.x;
    const float* p = s_jL + h * N_NODES;
    float v[16];
    float m = -INFINITY;
    #pragma unroll
    for (int i = 0; i < 16; i++) {
        v[i] = p[t + i * 256];
        m = fmaxf(m, v[i]);
    }
    #pragma unroll
    for (int mm = 32; mm >= 1; mm >>= 1) m = fmaxf(m, __shfl_xor(m, mm, 64));
    if ((t & 63) == 0) red[t >> 6] = m;
    __syncthreads();
    if (t == 0) {
        float mx = fmaxf(fmaxf(red[0], red[1]), fmaxf(red[2], red[3]));
        mxAll[h] = mx;
        mxs = mx;
    }
    __syncthreads();
    const float mx = mxs;
    #pragma unroll
    for (int i = 0; i < 16; i++) {
        float d = v[i] - mx;                      // <= 0
        F1h[h * N_NODES + t + i * 256] = (_Float16)exp2f(d);
        F2h[h * N_NODES + t + i * 256] = (_Float16)exp2f(0.2f * d);
    }
}

// ---------------- K3: exp-free P formation (separable factors) + LDS-staged B + nibble masks ----------------
__global__ __launch_bounds__(256, 4) void k_attn_mfma(const _Float16* __restrict__ WhFrag,
                                                      const float* __restrict__ s_iL,
                                                      const float* __restrict__ mxAll,
                                                      const _Float16* __restrict__ F1h,
                                                      const _Float16* __restrict__ F2h,
                                                      const unsigned long long* __restrict__ adjwT,
                                                      float* __restrict__ out0,
                                                      _Float16* __restrict__ partH,
                                                      float* __restrict__ lbuf) {
    __shared__ uint2 ktab4[16];             // nibble -> 2 packed halfword KEEP masks (128B: conflict-free)
    __shared__ _Float16 Bs[2][4096];        // 2 x 8KB: one c-chunk [kb(2)][nt(4)][lane(64)][8]
    if (threadIdx.x < 16) {
        unsigned int nib = threadIdx.x;
        unsigned int w0 = ((nib & 1u) ? 0xFFFFu : 0u) | ((nib & 2u) ? 0xFFFF0000u : 0u);
        unsigned int w1 = ((nib & 4u) ? 0xFFFFu : 0u) | ((nib & 8u) ? 0xFFFF0000u : 0u);
        ktab4[nib] = make_uint2(w0, w1);
    }

    const int tid  = threadIdx.x;
    const int h    = blockIdx.y;
    const int jc   = blockIdx.z;
    const int lane = tid & 63;
    const int w    = tid >> 6;
    const int i0   = blockIdx.x * 128 + w * 32;     // wave's 32 rows
    const int mrow = lane & 15;
    const int gl   = lane >> 4;
    const int gl8  = gl << 3;

    const float siL0 = s_iL[h * N_NODES + i0 + mrow];
    const float siL1 = s_iL[h * N_NODES + i0 + 16 + mrow];
    const float mxh  = mxAll[h];
    const float tm0 = siL0 + mxh, tm1 = siL1 + mxh;
    const float m0 = fmaxf(tm0, 0.2f * tm0);
    const float m1 = fmaxf(tm1, 0.2f * tm1);
    const _Float16 E1A = (_Float16)exp2f(tm0 - m0);
    const _Float16 E2A = (_Float16)exp2f(fmaf(0.2f, tm0, -m0));
    const _Float16 E1B = (_Float16)exp2f(tm1 - m1);
    const _Float16 E2B = (_Float16)exp2f(fmaf(0.2f, tm1, -m1));
    const half2_t e1a = {E1A, E1A}, e2a = {E2A, E2A};
    const half2_t e1b = {E1B, E1B}, e2b = {E2B, E2B};

    const _Float16* __restrict__ F1 = F1h + h * N_NODES;
    const _Float16* __restrict__ F2 = F2h + h * N_NODES;
    const _Float16* __restrict__ Bh = WhFrag + (size_t)h * (N_NODES * 64);

    half8_t vone;
    #pragma unroll
    for (int q = 0; q < 8; q++) vone[q] = (_Float16)1.0f;

    f32x4 accA0 = {0,0,0,0}, accA1 = {0,0,0,0}, accA2 = {0,0,0,0}, accA3 = {0,0,0,0};
    f32x4 accB0 = {0,0,0,0}, accB1 = {0,0,0,0}, accB2 = {0,0,0,0}, accB3 = {0,0,0,0};
    f32x4 acclA = {0,0,0,0}, acclB = {0,0,0,0};

    const int NC   = (N_NODES / 64) / JC;   // 16
    const int cbeg = jc * NC;
    const int cend = cbeg + NC;

    {   // prologue stage
        const _Float16* src = Bh + (size_t)cbeg * 4096 + tid * 8;
        *reinterpret_cast<half8_t*>(&Bs[0][tid * 8])        = *reinterpret_cast<const half8_t*>(src);
        *reinterpret_cast<half8_t*>(&Bs[0][2048 + tid * 8]) = *reinterpret_cast<const half8_t*>(src + 2048);
    }
    __syncthreads();

    int cur = 0;
    for (int c = cbeg; c < cend; c++) {
        half8_t n0, n1;
        const bool hasNext = (c + 1 < cend);
        if (hasNext) {
            const _Float16* src = Bh + (size_t)(c + 1) * 4096 + tid * 8;
            n0 = *reinterpret_cast<const half8_t*>(src);
            n1 = *reinterpret_cast<const half8_t*>(src + 2048);
        }

        uint2 word0 = *reinterpret_cast<const uint2*>(&adjwT[(size_t)c * N_NODES + i0 + mrow]);
        uint2 word1 = *reinterpret_cast<const uint2*>(&adjwT[(size_t)c * N_NODES + i0 + 16 + mrow]);

        #pragma unroll
        for (int kb = 0; kb < 2; kb++) {
            const int jb = c * 64 + kb * 32 + 8 * gl;
            half8_t f1v = *reinterpret_cast<const half8_t*>(&F1[jb]);
            half8_t f2v = *reinterpret_cast<const half8_t*>(&F2[jb]);
            unsigned int bm0 = ((kb ? word0.y : word0.x) >> gl8) & 0xFFu;
            unsigned int bm1 = ((kb ? word1.y : word1.x) >> gl8) & 0xFFu;
            uint2 klo0 = ktab4[bm0 & 15u], khi0 = ktab4[bm0 >> 4];
            uint2 klo1 = ktab4[bm1 & 15u], khi1 = ktab4[bm1 >> 4];
            uint4 mk0 = {klo0.x, klo0.y, khi0.x, khi0.y};
            uint4 mk1 = {klo1.x, klo1.y, khi1.x, khi1.y};

            uint4 f1u = __builtin_bit_cast(uint4, f1v);
            uint4 f2u = __builtin_bit_cast(uint4, f2v);
            uint4 p0u, p1u;
            #pragma unroll
            for (int q = 0; q < 4; q++) {
                unsigned int f1w = (q == 0) ? f1u.x : (q == 1) ? f1u.y : (q == 2) ? f1u.z : f1u.w;
                unsigned int f2w = (q == 0) ? f2u.x : (q == 1) ? f2u.y : (q == 2) ? f2u.z : f2u.w;
                half2_t f12 = __builtin_bit_cast(half2_t, f1w);
                half2_t f22 = __builtin_bit_cast(half2_t, f2w);
                half2_t pA = __builtin_elementwise_max(e1a * f12, e2a * f22);  // exp-free P
                half2_t pB = __builtin_elementwise_max(e1b * f12, e2b * f22);
                unsigned int ka  = (q == 0) ? mk0.x : (q == 1) ? mk0.y : (q == 2) ? mk0.z : mk0.w;
                unsigned int kbm = (q == 0) ? mk1.x : (q == 1) ? mk1.y : (q == 2) ? mk1.z : mk1.w;
                unsigned int pa = __builtin_bit_cast(unsigned int, pA) & ka;
                unsigned int pb = __builtin_bit_cast(unsigned int, pB) & kbm;
                if (q == 0) { p0u.x = pa; p1u.x = pb; }
                else if (q == 1) { p0u.y = pa; p1u.y = pb; }
                else if (q == 2) { p0u.z = pa; p1u.z = pb; }
                else { p0u.w = pa; p1u.w = pb; }
            }
            half8_t af0 = __builtin_bit_cast(half8_t, p0u);
            half8_t af1 = __builtin_bit_cast(half8_t, p1u);

            const _Float16* Bk = &Bs[cur][kb * 2048 + lane * 8];
            half8_t b0  = *reinterpret_cast<const half8_t*>(Bk);
            half8_t b1v = *reinterpret_cast<const half8_t*>(Bk + 512);
            half8_t b2  = *reinterpret_cast<const half8_t*>(Bk + 1024);
            half8_t b3  = *reinterpret_cast<const half8_t*>(Bk + 1536);

            accA0 = __builtin_amdgcn_mfma_f32_16x16x32_f16(af0, b0,  accA0, 0, 0, 0);
            accB0 = __builtin_amdgcn_mfma_f32_16x16x32_f16(af1, b0,  accB0, 0, 0, 0);
            accA1 = __builtin_amdgcn_mfma_f32_16x16x32_f16(af0, b1v, accA1, 0, 0, 0);
            accB1 = __builtin_amdgcn_mfma_f32_16x16x32_f16(af1, b1v, accB1, 0, 0, 0);
            accA2 = __builtin_amdgcn_mfma_f32_16x16x32_f16(af0, b2,  accA2, 0, 0, 0);
            accB2 = __builtin_amdgcn_mfma_f32_16x16x32_f16(af1, b2,  accB2, 0, 0, 0);
            accA3 = __builtin_amdgcn_mfma_f32_16x16x32_f16(af0, b3,  accA3, 0, 0, 0);
            accB3 = __builtin_amdgcn_mfma_f32_16x16x32_f16(af1, b3,  accB3, 0, 0, 0);
            acclA = __builtin_amdgcn_mfma_f32_16x16x32_f16(af0, vone, acclA, 0, 0, 0);
            acclB = __builtin_amdgcn_mfma_f32_16x16x32_f16(af1, vone, acclB, 0, 0, 0);
        }

        if (hasNext) {
            *reinterpret_cast<half8_t*>(&Bs[cur ^ 1][tid * 8])        = n0;
            *reinterpret_cast<half8_t*>(&Bs[cur ^ 1][2048 + tid * 8]) = n1;
        }
        __syncthreads();
        cur ^= 1;
    }

    float* lp = lbuf + (size_t)jc * (H_HEADS * N_NODES);
    if (mrow == 0) {
        #pragma unroll
        for (int r = 0; r < 4; r++) {
            lp[h * N_NODES + i0 + 4 * gl + r]      = acclA[r];
            lp[h * N_NODES + i0 + 16 + 4 * gl + r] = acclB[r];
        }
    }
    if (jc == 0) {
        #pragma unroll
        for (int r = 0; r < 4; r++) {
            size_t obA = ((size_t)h * N_NODES + i0 + 4 * gl + r) * 64 + mrow;
            size_t obB = ((size_t)h * N_NODES + i0 + 16 + 4 * gl + r) * 64 + mrow;
            out0[obA + 0]  = accA0[r];
            out0[obA + 16] = accA1[r];
            out0[obA + 32] = accA2[r];
            out0[obA + 48] = accA3[r];
            out0[obB + 0]  = accB0[r];
            out0[obB + 16] = accB1[r];
            out0[obB + 32] = accB2[r];
            out0[obB + 48] = accB3[r];
        }
    } else {
        _Float16* op = partH + (size_t)(jc - 1) * ((size_t)H_HEADS * N_NODES * F_OUT);
        #pragma unroll
        for (int r = 0; r < 4; r++) {
            size_t obA = ((size_t)h * N_NODES + i0 + 4 * gl + r) * 64 + mrow;
            size_t obB = ((size_t)h * N_NODES + i0 + 16 + 4 * gl + r) * 64 + mrow;
            op[obA + 0]  = (_Float16)accA0[r];
            op[obA + 16] = (_Float16)accA1[r];
            op[obA + 32] = (_Float16)accA2[r];
            op[obA + 48] = (_Float16)accA3[r];
            op[obB + 0]  = (_Float16)accB0[r];
            op[obB + 16] = (_Float16)accB1[r];
            op[obB + 32] = (_Float16)accB2[r];
            op[obB + 48] = (_Float16)accB3[r];
        }
    }
}

// ---------------- K4: out = (out + sum f16 partials) / sum l ----------------
__global__ __launch_bounds__(256) void k_norm(float* __restrict__ out,
                                              const _Float16* __restrict__ partH,
                                              const float* __restrict__ lbuf) {
    const int HN = H_HEADS * N_NODES;
    int idx = blockIdx.x * 256 + threadIdx.x;        // float4 index
    int row = idx >> 4;
    float inv = 1.0f / (lbuf[row] + lbuf[HN + row] + lbuf[2 * HN + row] + lbuf[3 * HN + row]);
    float4 a = reinterpret_cast<const float4*>(out)[idx];
    float s0 = a.x, s1 = a.y, s2 = a.z, s3 = a.w;
    #pragma unroll
    for (int p = 0; p < 3; p++) {
        half4_t hp = *reinterpret_cast<const half4_t*>(
            &partH[(size_t)p * ((size_t)H_HEADS * N_NODES * F_OUT) + (size_t)idx * 4]);
        s0 += (float)hp[0]; s1 += (float)hp[1]; s2 += (float)hp[2]; s3 += (float)hp[3];
    }
    float4 v = {s0 * inv, s1 * inv, s2 * inv, s3 * inv};
    reinterpret_cast<float4*>(out)[idx] = v;
}

// ---------------- launch ----------------
extern "C" void kernel_launch(void* const* d_in, const int* in_sizes, int n_in,
                              void* d_out, int out_size, void* d_ws, size_t ws_size,
                              hipStream_t stream) {
    const float* x     = (const float*)d_in[0];
    const int*   adj   = (const int*)d_in[1];
    const float* W     = (const float*)d_in[2];
    const float* a_src = (const float*)d_in[3];
    const float* a_tgt = (const float*)d_in[4];
    float* out = (float*)d_out;

    // workspace via accumulating allocator (R7 lesson: no hand-computed offsets)
    char* ws = (char*)d_ws;
    size_t off = 0;
    auto alloc = [&](size_t bytes) -> char* {
        char* p = ws + off;
        off += (bytes + 255) & ~(size_t)255;
        return p;
    };
    _Float16* WhFrag = (_Float16*)alloc((size_t)H_HEADS * N_NODES * F_OUT * 2);        // 4 MB
    _Float16* wfrag  = (_Float16*)alloc((size_t)H_HEADS * 16 * 4 * 64 * 8 * 2);        // 512 KB
    float* s_iL      = (float*)alloc((size_t)H_HEADS * N_NODES * 4);                   // 128 KB
    float* s_jL      = (float*)alloc((size_t)H_HEADS * N_NODES * 4);                   // 128 KB
    _Float16* F1h    = (_Float16*)alloc((size_t)H_HEADS * N_NODES * 2);                // 64 KB
    _Float16* F2h    = (_Float16*)alloc((size_t)H_HEADS * N_NODES * 2);                // 64 KB
    float* mxAll     = (float*)alloc((size_t)H_HEADS * 4);                             // 32 B
    float* lbuf      = (float*)alloc((size_t)JC * H_HEADS * N_NODES * 4);              // 512 KB
    _Float16* partH  = (_Float16*)alloc((size_t)(JC - 1) * H_HEADS * N_NODES * F_OUT * 2); // 12 MB
    unsigned long long* adjwT = (unsigned long long*)alloc((size_t)N_NODES * (N_NODES / 64) * 8); // 2 MB
    (void)ws_size;

    k_prep<<<2176, 256, 0, stream>>>(adj, W, adjwT, wfrag);
    k_wh_mfma<<<N_NODES / 16, 512, 0, stream>>>(x, wfrag, a_src, a_tgt, WhFrag, s_iL, s_jL);
    k_hmax<<<H_HEADS, 256, 0, stream>>>(s_jL, mxAll, F1h, F2h);
    k_attn_mfma<<<dim3(N_NODES / 128, H_HEADS, JC), 256, 0, stream>>>(WhFrag, s_iL, mxAll, F1h, F2h,
                                                                      adjwT, out, partH, lbuf);
    k_norm<<<(H_HEADS * N_NODES * F_OUT / 4) / 256, 256, 0, stream>>>(out, partH, lbuf);
}